// Round 2
// baseline (65342.914 us; speedup 1.0000x reference)
//
#include <hip/hip_runtime.h>
#include <cstddef>

// Problem constants
#define NV   30
#define NDH  512
#define NE   256
#define NKV  128
#define NB   256
#define NT   800
#define NL   300
#define NKX  896   // E + KV + DH

#define PRED_SIZE (NB*NL*NV)   // 2304000 floats; attn_plot follows (NL*NT)

// workspace float offsets
#define WS_X   0
#define WS_H1  (NB*NKX)                 // 229376
#define WS_C1  (WS_H1 + NB*NDH)
#define WS_H2  (WS_C1 + NB*NDH)         // 2 buffers of NB*NKV
#define WS_C2  (WS_H2 + 2*NB*NKV)

struct DecParams {
  const float* key; const float* val; const int* elen; const int* y;
  const float* emb;
  const float* wi1; const float* wh1; const float* bi1; const float* bh1;
  const float* wi2; const float* wh2; const float* bi2; const float* bh2;
  const float* ob;
  float* out; float* ws;
};

__device__ __forceinline__ float sigm(float x)  { return 1.0f/(1.0f + __expf(-x)); }
__device__ __forceinline__ float tanh_f(float x){ return 1.0f - 2.0f/(__expf(2.0f*x)+1.0f); }

// ---------------- init: h/c zero, x0 = [emb[SOS] | value[:,0,:] | zeros] ----------------
__global__ void __launch_bounds__(256)
k_init(DecParams P)
{
  const int tid = threadIdx.x;
  const int b   = blockIdx.x;
  float* X   = P.ws + WS_X;
  float* H1  = P.ws + WS_H1;
  float* C1  = P.ws + WS_C1;
  float* H2b = P.ws + WS_H2;
  float* C2  = P.ws + WS_C2;

  X[(size_t)b*NKX + tid] = P.emb[tid];                       // emb row 0 (SOS) (zeroed row)
  if (tid < 128) X[(size_t)b*NKX + 256 + tid] = P.val[(size_t)b*NT*NKV + tid];
  X[(size_t)b*NKX + 384 + tid] = 0.0f;
  X[(size_t)b*NKX + 640 + tid] = 0.0f;
  H1[(size_t)b*NDH + tid] = 0.0f; H1[(size_t)b*NDH + 256 + tid] = 0.0f;
  C1[(size_t)b*NDH + tid] = 0.0f; C1[(size_t)b*NDH + 256 + tid] = 0.0f;
  if (tid < 128) { H2b[(size_t)b*NKV + tid] = 0.0f; C2[(size_t)b*NKV + tid] = 0.0f; }
}

// ---------------- Phase A: LSTM1  (g = [x|ctx|h1] . W^T) ----------------
__global__ void __launch_bounds__(256)
k_stepA(DecParams P, int t)
{
  (void)t;
  __shared__ struct { float xs[32][66]; float wl[32][34]; } sm;
  const int tid = threadIdx.x;
  const int bid = blockIdx.x;
  float* X   = P.ws + WS_X;
  float* H1  = P.ws + WS_H1;
  float* C1  = P.ws + WS_C1;

  const int bt = bid >> 6;           // 0..3  -> 64 b
  const int jt = bid & 63;           // 0..63 -> 8 j
  const int b0 = bt * 64;
  const int j0 = jt * 8;
  const int bq = tid & 31;           // b pair index
  const int jq = tid >> 5;           // 0..7
  const int j  = j0 + jq;

  float acc0[4] = {0.f,0.f,0.f,0.f};
  float acc1[4] = {0.f,0.f,0.f,0.f};

  const int b_ld = tid >> 2;         // 0..63
  const int k0l  = (tid & 3) * 8;    // 0..24

#pragma unroll 1
  for (int kc = 0; kc < NKX; kc += 32) {
    __syncthreads();
    // stage x chunk transposed: xs[k][b]
    {
      const float4* s4 = (const float4*)(X + (size_t)(b0 + b_ld)*NKX + kc + k0l);
      float4 f0 = s4[0], f1 = s4[1];
      sm.xs[k0l+0][b_ld] = f0.x; sm.xs[k0l+1][b_ld] = f0.y;
      sm.xs[k0l+2][b_ld] = f0.z; sm.xs[k0l+3][b_ld] = f0.w;
      sm.xs[k0l+4][b_ld] = f1.x; sm.xs[k0l+5][b_ld] = f1.y;
      sm.xs[k0l+6][b_ld] = f1.z; sm.xs[k0l+7][b_ld] = f1.w;
    }
    // stage weight chunk: wl[r = g*8+jj][k]
    {
      const int r  = tid >> 3;       // 0..31
      const int kk = (tid & 7) * 4;  // 0..28
      const int g  = r >> 3;
      const int jj = r & 7;
      const int grow = g*NDH + j0 + jj;
      float4 f;
      if (kc < 384) f = *(const float4*)(P.wi1 + (size_t)grow*384 + kc + kk);
      else          f = *(const float4*)(P.wh1 + (size_t)grow*NDH + (kc-384) + kk);
      sm.wl[r][kk+0] = f.x; sm.wl[r][kk+1] = f.y;
      sm.wl[r][kk+2] = f.z; sm.wl[r][kk+3] = f.w;
    }
    __syncthreads();
#pragma unroll
    for (int k = 0; k < 32; k += 2) {
      float2 xa = *(const float2*)&sm.xs[k  ][2*bq];
      float2 xb = *(const float2*)&sm.xs[k+1][2*bq];
#pragma unroll
      for (int g = 0; g < 4; ++g) {
        float2 w = *(const float2*)&sm.wl[g*8+jq][k];
        acc0[g] += w.x*xa.x + w.y*xb.x;
        acc1[g] += w.x*xa.y + w.y*xb.y;
      }
    }
  }
  // finalize the 2 batch rows
  float bia[4];
#pragma unroll
  for (int g = 0; g < 4; ++g) bia[g] = P.bi1[g*NDH + j] + P.bh1[g*NDH + j];
  {
    const int b = b0 + 2*bq;
    float ig = sigm(acc0[0] + bia[0]);
    float fg = sigm(acc0[1] + bia[1]);
    float gg = tanh_f(acc0[2] + bia[2]);
    float og = sigm(acc0[3] + bia[3]);
    float cn = fg * C1[(size_t)b*NDH + j] + ig * gg;
    C1[(size_t)b*NDH + j] = cn;
    H1[(size_t)b*NDH + j] = og * tanh_f(cn);
  }
  {
    const int b = b0 + 2*bq + 1;
    float ig = sigm(acc1[0] + bia[0]);
    float fg = sigm(acc1[1] + bia[1]);
    float gg = tanh_f(acc1[2] + bia[2]);
    float og = sigm(acc1[3] + bia[3]);
    float cn = fg * C1[(size_t)b*NDH + j] + ig * gg;
    C1[(size_t)b*NDH + j] = cn;
    H1[(size_t)b*NDH + j] = og * tanh_f(cn);
  }
}

// ---------------- Phase B: LSTM2 ----------------
__global__ void __launch_bounds__(256)
k_stepB(DecParams P, int t)
{
  __shared__ struct { float hs[64][33]; float w2s[16][516]; float whs[16][132]; float part[4][128]; } sm;
  const int tid = threadIdx.x;
  const int bid = blockIdx.x;
  const float* H1  = P.ws + WS_H1;
  float*       C2  = P.ws + WS_C2;
  const float* H2p = P.ws + WS_H2 + (size_t)(t & 1) * NB*NKV;
  float*       H2n = P.ws + WS_H2 + (size_t)((t+1) & 1) * NB*NKV;

  const int bt = bid >> 5;           // 0..7  -> 32 b
  const int jt = bid & 31;           // 0..31 -> 4 j2
  const int b0 = bt * 32;
  const int j0 = jt * 4;
  const int bq  = tid & 31;
  const int jq  = (tid >> 5) & 3;
  const int seg = tid >> 7;          // 0: w_ih2 (K=512 over h1), 1: w_hh2 (K=128 over h2p)
  const int j2  = j0 + jq;

  // stage weight slices into LDS (once per step)
#pragma unroll
  for (int i = 0; i < 8; ++i) {
    int f = (tid + 256*i) * 4;       // 0..8188
    int r = f >> 9; int k = f & 511;
    int g = r >> 2; int jj = r & 3;
    float4 v = *(const float4*)(P.wi2 + (size_t)(g*NKV + j0 + jj)*NDH + k);
    *(float4*)&sm.w2s[r][k] = v;
  }
#pragma unroll
  for (int i = 0; i < 2; ++i) {
    int f = (tid + 256*i) * 4;       // 0..2044
    int r = f >> 7; int k = f & 127;
    int g = r >> 2; int jj = r & 3;
    float4 v = *(const float4*)(P.wh2 + (size_t)(g*NKV + j0 + jj)*NKV + k);
    *(float4*)&sm.whs[r][k] = v;
  }

  float acc[4] = {0.f,0.f,0.f,0.f};
  const int b_ld = tid >> 3;         // 0..31
  const int k0l  = (tid & 7) * 8;    // 0..56

#pragma unroll 1
  for (int c = 0; c < 10; ++c) {
    __syncthreads();
    {
      const float* src = (c < 8)
        ? (H1  + (size_t)(b0 + b_ld)*NDH + c*64 + k0l)
        : (H2p + (size_t)(b0 + b_ld)*NKV + (c-8)*64 + k0l);
      const float4* s4 = (const float4*)src;
      float4 f0 = s4[0], f1 = s4[1];
      sm.hs[k0l+0][b_ld] = f0.x; sm.hs[k0l+1][b_ld] = f0.y;
      sm.hs[k0l+2][b_ld] = f0.z; sm.hs[k0l+3][b_ld] = f0.w;
      sm.hs[k0l+4][b_ld] = f1.x; sm.hs[k0l+5][b_ld] = f1.y;
      sm.hs[k0l+6][b_ld] = f1.z; sm.hs[k0l+7][b_ld] = f1.w;
    }
    __syncthreads();
    if (c < 8) {
      if (seg == 0) {
#pragma unroll
        for (int k = 0; k < 64; k += 2) {
          float x0 = sm.hs[k][bq], x1 = sm.hs[k+1][bq];
#pragma unroll
          for (int g = 0; g < 4; ++g) {
            float2 w = *(const float2*)&sm.w2s[g*4+jq][c*64 + k];
            acc[g] += w.x*x0 + w.y*x1;
          }
        }
      }
    } else {
      if (seg == 1) {
#pragma unroll
        for (int k = 0; k < 64; k += 2) {
          float x0 = sm.hs[k][bq], x1 = sm.hs[k+1][bq];
#pragma unroll
          for (int g = 0; g < 4; ++g) {
            float2 w = *(const float2*)&sm.whs[g*4+jq][(c-8)*64 + k];
            acc[g] += w.x*x0 + w.y*x1;
          }
        }
      }
    }
  }
  __syncthreads();
  if (seg == 1) {
#pragma unroll
    for (int g = 0; g < 4; ++g) sm.part[g][tid & 127] = acc[g];
  }
  __syncthreads();
  if (seg == 0) {
    const int b = b0 + bq;
#pragma unroll
    for (int g = 0; g < 4; ++g) acc[g] += sm.part[g][tid];
    float ig = sigm(acc[0] + P.bi2[0*NKV+j2] + P.bh2[0*NKV+j2]);
    float fg = sigm(acc[1] + P.bi2[1*NKV+j2] + P.bh2[1*NKV+j2]);
    float gg = tanh_f(acc[2] + P.bi2[2*NKV+j2] + P.bh2[2*NKV+j2]);
    float og = sigm(acc[3] + P.bi2[3*NKV+j2] + P.bh2[3*NKV+j2]);
    float cn = fg * C2[(size_t)b*NKV + j2] + ig * gg;
    C2[(size_t)b*NKV + j2] = cn;
    H2n[(size_t)b*NKV + j2] = og * tanh_f(cn);
  }
}

// ---------------- Phase C: attention + prediction + next x ----------------
__global__ void __launch_bounds__(256)
k_stepC(DecParams P, int t)
{
  __shared__ struct { float e[NT]; float qc[256]; float red[8]; float ctxp[8][132]; } sm;
  const int tid = threadIdx.x;
  const int b   = blockIdx.x;
  float* X   = P.ws + WS_X;
  float* H1  = P.ws + WS_H1;
  const float* H2n = P.ws + WS_H2 + (size_t)((t+1) & 1) * NB*NKV + (size_t)b*NKV;

  const int len = P.elen[b];
  if (tid < 128) sm.qc[tid] = H2n[tid];
  __syncthreads();

  const int wid = tid >> 6, lane = tid & 63;
  const float q0 = sm.qc[lane], q1 = sm.qc[64 + lane];
  for (int tt = wid; tt < len; tt += 4) {
    const float* kr = P.key + ((size_t)b*NT + tt)*NKV;
    float p = kr[lane]*q0 + kr[64+lane]*q1;
    p += __shfl_xor(p, 1);  p += __shfl_xor(p, 2);  p += __shfl_xor(p, 4);
    p += __shfl_xor(p, 8);  p += __shfl_xor(p, 16); p += __shfl_xor(p, 32);
    if (lane == 0) sm.e[tt] = p;
  }
  for (int tt = len + tid; tt < NT; tt += 256) sm.e[tt] = -1e9f;
  __syncthreads();

  // softmax (block reduce)
  float m = -3.0e38f;
#pragma unroll
  for (int i = 0; i < 4; ++i) { int tt = tid + 256*i; if (tt < NT) m = fmaxf(m, sm.e[tt]); }
  m = fmaxf(m, __shfl_xor(m, 1));  m = fmaxf(m, __shfl_xor(m, 2));
  m = fmaxf(m, __shfl_xor(m, 4));  m = fmaxf(m, __shfl_xor(m, 8));
  m = fmaxf(m, __shfl_xor(m, 16)); m = fmaxf(m, __shfl_xor(m, 32));
  if (lane == 0) sm.red[wid] = m;
  __syncthreads();
  m = fmaxf(fmaxf(sm.red[0], sm.red[1]), fmaxf(sm.red[2], sm.red[3]));
  float s = 0.0f;
#pragma unroll
  for (int i = 0; i < 4; ++i) { int tt = tid + 256*i; if (tt < NT) s += __expf(sm.e[tt] - m); }
  s += __shfl_xor(s, 1);  s += __shfl_xor(s, 2);  s += __shfl_xor(s, 4);
  s += __shfl_xor(s, 8);  s += __shfl_xor(s, 16); s += __shfl_xor(s, 32);
  __syncthreads();
  if (lane == 0) sm.red[4 + wid] = s;
  __syncthreads();
  const float inv = 1.0f / (sm.red[4] + sm.red[5] + sm.red[6] + sm.red[7]);
#pragma unroll
  for (int i = 0; i < 4; ++i) {
    int tt = tid + 256*i;
    if (tt < NT) {
      float a = __expf(sm.e[tt] - m) * inv;
      sm.e[tt] = a;
      if (b == 0) P.out[PRED_SIZE + (size_t)t*NT + tt] = a;
    }
  }
  __syncthreads();

  // ctx = attn @ value   (skip invalid t; attn there is 0)
  const int kq = tid & 31, tq = tid >> 5;
  float4 acc = {0.f,0.f,0.f,0.f};
  for (int tt = tq; tt < len; tt += 8) {
    float a = sm.e[tt];
    const float4* vr = (const float4*)(P.val + ((size_t)b*NT + tt)*NKV);
    float4 v = vr[kq];
    acc.x += a*v.x; acc.y += a*v.y; acc.z += a*v.z; acc.w += a*v.w;
  }
  *(float4*)&sm.ctxp[tq][4*kq] = acc;
  __syncthreads();
  if (tq == 0) {
    float4 sv = {0.f,0.f,0.f,0.f};
#pragma unroll
    for (int r = 0; r < 8; ++r) {
      float4 v = *(const float4*)&sm.ctxp[r][4*kq];
      sv.x += v.x; sv.y += v.y; sv.z += v.z; sv.w += v.w;
    }
    *(float4*)&sm.qc[128 + 4*kq] = sv;                         // [q|ctx] for pred
    *(float4*)(X + (size_t)b*NKX + 256 + 4*kq) = sv;           // x_next ctx part
  }
  __syncthreads();

  // pred = [q|ctx] @ emb^T + out_bias
  {
    const int vv = tid >> 3, kq8 = tid & 7;
    if (vv < NV) {
      const float4* e4 = (const float4*)(P.emb + (size_t)vv*NE + kq8*32);
      const float4* q4 = (const float4*)&sm.qc[kq8*32];
      float p = 0.0f;
#pragma unroll
      for (int i = 0; i < 8; ++i) {
        float4 a = e4[i], q = q4[i];
        p += a.x*q.x + a.y*q.y + a.z*q.z + a.w*q.w;
      }
      p += __shfl_xor(p, 1); p += __shfl_xor(p, 2); p += __shfl_xor(p, 4);
      if (kq8 == 0) P.out[((size_t)b*NL + t)*NV + vv] = p + P.ob[vv];
    }
  }

  // x_next: emb(y[b][t]) and h1 copy (ctx already written)
  {
    const int tok = P.y[(size_t)b*NL + t];
    X[(size_t)b*NKX + tid]       = P.emb[(size_t)tok*NE + tid];
    X[(size_t)b*NKX + 384 + tid] = H1[(size_t)b*NDH + tid];
    X[(size_t)b*NKX + 640 + tid] = H1[(size_t)b*NDH + 256 + tid];
  }
}

extern "C" void kernel_launch(void* const* d_in, const int* in_sizes, int n_in,
                              void* d_out, int out_size, void* d_ws, size_t ws_size,
                              hipStream_t stream) {
  (void)in_sizes; (void)n_in; (void)out_size; (void)ws_size;
  DecParams P;
  P.key  = (const float*)d_in[0];
  P.val  = (const float*)d_in[1];
  P.elen = (const int*)d_in[2];
  P.y    = (const int*)d_in[3];
  P.emb  = (const float*)d_in[4];
  P.wi1  = (const float*)d_in[5];
  P.wh1  = (const float*)d_in[6];
  P.bi1  = (const float*)d_in[7];
  P.bh1  = (const float*)d_in[8];
  P.wi2  = (const float*)d_in[9];
  P.wh2  = (const float*)d_in[10];
  P.bi2  = (const float*)d_in[11];
  P.bh2  = (const float*)d_in[12];
  P.ob   = (const float*)d_in[13];
  P.out  = (float*)d_out;
  P.ws   = (float*)d_ws;

  hipLaunchKernelGGL(k_init, dim3(NB), dim3(256), 0, stream, P);
  for (int t = 0; t < NL; ++t) {
    hipLaunchKernelGGL(k_stepA, dim3(NB), dim3(256), 0, stream, P, t);
    hipLaunchKernelGGL(k_stepB, dim3(NB), dim3(256), 0, stream, P, t);
    hipLaunchKernelGGL(k_stepC, dim3(NB), dim3(256), 0, stream, P, t);
  }
}

// Round 3
// 17863.644 us; speedup vs baseline: 3.6579x; 3.6579x over previous
//
#include <hip/hip_runtime.h>
#include <cstddef>

// Problem constants
#define NV   30
#define NDH  512
#define NE   256
#define NKV  128
#define NB   256
#define NT   800
#define NL   300
#define NKX  896   // E + KV + DH

#define PRED_SIZE (NB*NL*NV)   // 2304000 floats; attn_plot (NL*NT) follows

typedef float v4f __attribute__((ext_vector_type(4)));
typedef float v2f __attribute__((ext_vector_type(2)));

// workspace float offsets
// Xt[896][256]: rows 0..255 emb(y_prev), 256..383 ctx, 384..895 h1  (all [k][b])
#define OFF_XT  0
#define OFF_C1  229376                 // C1t[512][256]  ([j][b])
#define OFF_H2  (OFF_C1 + 131072)      // H2t[2][128][256] ([par][j][b])
#define OFF_C2  (OFF_H2 + 65536)       // C2[256][128]   ([b][j])
#define OFF_GP  (OFF_C2 + 32768)       // Gp[4][2048][256] ([kt][r][b])
#define OFF_BP  (OFF_GP + 2097152)     // Bp[4][256][512]  ([kt][b][r])
// total = 3,080,192 floats = 12.3 MB

struct DecParams {
  const float* key; const float* val; const int* elen; const int* y;
  const float* emb;
  const float* wi1; const float* wh1; const float* bi1; const float* bh1;
  const float* wi2; const float* wh2; const float* bi2; const float* bh2;
  const float* ob;
  float* out; float* ws;
};

__device__ __forceinline__ float sigm(float x)  { return 1.0f/(1.0f + __expf(-x)); }
__device__ __forceinline__ float tanh_f(float x){ return 1.0f - 2.0f/(__expf(2.0f*x)+1.0f); }

// ---------------- init ----------------
// zero Xt(emb+h1)/C1t/H2t/C2; Xt ctx rows <- value[:,0,:]
__global__ void __launch_bounds__(256)
k_init(DecParams P)
{
  const int idx = blockIdx.x * 256 + threadIdx.x;   // grid 1792*256 = 458752
  float* ws = P.ws;
  if (idx < 229376) {                                // Xt
    const int row = idx >> 8, b = idx & 255;
    float v = 0.0f;
    if (row >= 256 && row < 384) v = P.val[(size_t)b*NT*NKV + (row-256)];
    ws[OFF_XT + idx] = v;
  } else {
    ws[idx] = 0.0f;                                  // C1t, H2t, C2 (idx < 458752)
  }
}

// ---------------- Phase A: gates1 partial GEMM ----------------
// g_partial[kt][r][b] = sum_{k in kt-range} W1[r][k] * x[b][k]
// grid 512 = bt(4:64b) x jt(32:64r) x kt(4:K=224); 256 threads; thread tile 4b x 4r
__global__ void __launch_bounds__(256)
k_stepA(DecParams P)
{
  __shared__ float xs[32][68];     // [k][b]
  __shared__ float wr[64][36];     // [r][k]
  const int tid = threadIdx.x;
  const int bid = blockIdx.x;
  const int bt = bid & 3, jt = (bid >> 2) & 31, kt = bid >> 7;
  const int b0 = bt * 64, r0 = jt * 64;
  const int bq = tid & 15, rq = tid >> 4;

  const float* Xt = P.ws + OFF_XT;
  float* Gp = P.ws + OFF_GP;

  v4f acc[4];
#pragma unroll
  for (int i = 0; i < 4; ++i) acc[i] = (v4f)0.0f;

  const int kx_ld = tid >> 3, bx8 = (tid & 7) * 8;   // x staging
  const int rw_ld = tid >> 2, kw8 = (tid & 3) * 8;   // w staging

#pragma unroll 1
  for (int cc = 0; cc < 7; ++cc) {
    const int kg0 = kt * 224 + cc * 32;
    __syncthreads();
    {  // stage x: Xt[k][b] -> xs[k][b], no transpose, coalesced
      const v4f* src = (const v4f*)(Xt + (size_t)(kg0 + kx_ld) * 256 + b0 + bx8);
      v4f f0 = src[0], f1 = src[1];
      *(v4f*)&xs[kx_ld][bx8]     = f0;
      *(v4f*)&xs[kx_ld][bx8 + 4] = f1;
    }
    {  // stage w row-major: W1[r][k] -> wr[r][k]
      const int row = r0 + rw_ld;
      const int kg = kg0 + kw8;
      const float* src = (kg < 384) ? (P.wi1 + (size_t)row*384 + kg)
                                    : (P.wh1 + (size_t)row*512 + (kg - 384));
      v4f f0 = ((const v4f*)src)[0], f1 = ((const v4f*)src)[1];
      *(v4f*)&wr[rw_ld][kw8]     = f0;
      *(v4f*)&wr[rw_ld][kw8 + 4] = f1;
    }
    __syncthreads();
#pragma unroll
    for (int q = 0; q < 8; ++q) {
      v4f x0 = *(const v4f*)&xs[q*4+0][bq*4];
      v4f x1 = *(const v4f*)&xs[q*4+1][bq*4];
      v4f x2 = *(const v4f*)&xs[q*4+2][bq*4];
      v4f x3 = *(const v4f*)&xs[q*4+3][bq*4];
#pragma unroll
      for (int ri = 0; ri < 4; ++ri) {
        v4f w = *(const v4f*)&wr[rq*4+ri][q*4];
        acc[ri] += w[0]*x0 + w[1]*x1 + w[2]*x2 + w[3]*x3;
      }
    }
  }
  // store partials, coalesced over b
#pragma unroll
  for (int ri = 0; ri < 4; ++ri) {
    *(v4f*)&Gp[((size_t)kt*2048 + r0 + rq*4 + ri)*256 + b0 + bq*4] = acc[ri];
  }
}

// ---------------- Afin: sum partials + LSTM1 activations ----------------
// grid 512 (j), 256 threads (b). Writes h1 -> Xt[384+j][b], c1 -> C1t[j][b]
__global__ void __launch_bounds__(256)
k_afin(DecParams P)
{
  const int j = blockIdx.x;
  const int b = threadIdx.x;
  const float* Gp = P.ws + OFF_GP;
  float* Xt = P.ws + OFF_XT;
  float* C1 = P.ws + OFF_C1;

  float s[4];
#pragma unroll
  for (int g = 0; g < 4; ++g) {
    const size_t base = ((size_t)g*512 + j)*256 + b;
    s[g] = Gp[base] + Gp[2048*256 + base] + Gp[2*2048*256 + base] + Gp[3*2048*256 + base]
         + P.bi1[g*512 + j] + P.bh1[g*512 + j];
  }
  const float ig = sigm(s[0]);
  const float fg = sigm(s[1]);
  const float gg = tanh_f(s[2]);
  const float og = sigm(s[3]);
  const float cn = fg * C1[(size_t)j*256 + b] + ig * gg;
  C1[(size_t)j*256 + b] = cn;
  Xt[(size_t)(384 + j)*256 + b] = og * tanh_f(cn);
}

// ---------------- Phase B: gates2 partial GEMM ----------------
// grid 512 = bt(8:32b) x jt(16:32r) x kt(4:K=160); 256 threads; thread tile 2b x 2r
__global__ void __launch_bounds__(256)
k_stepB(DecParams P, int t)
{
  __shared__ float xs2[32][36];   // [k][b]
  __shared__ float wr2[32][36];   // [r][k]
  const int tid = threadIdx.x;
  const int bid = blockIdx.x;
  const int bt = bid & 7, jt = (bid >> 3) & 15, kt = bid >> 7;
  const int b0 = bt * 32, r0 = jt * 32;
  const int bq = tid & 15, rq = tid >> 4;

  const float* Xt = P.ws + OFF_XT;
  const float* H2p = P.ws + OFF_H2 + (size_t)(t & 1) * 32768;
  float* Bp = P.ws + OFF_BP;

  v2f acc[2] = {(v2f)0.0f, (v2f)0.0f};

  const int kx_ld = tid >> 3, bx4 = (tid & 7) * 4;
  const int rw_ld = tid >> 3, kw4 = (tid & 7) * 4;

#pragma unroll 1
  for (int cc = 0; cc < 5; ++cc) {
    const int kg0 = kt * 160 + cc * 32;
    __syncthreads();
    {  // stage x from Xt h1-rows or H2p, both [k][b]: no transpose
      const int kg = kg0 + kx_ld;
      const float* src = (kg < 512) ? (Xt + (size_t)(384 + kg)*256 + b0 + bx4)
                                    : (H2p + (size_t)(kg - 512)*256 + b0 + bx4);
      *(v4f*)&xs2[kx_ld][bx4] = *(const v4f*)src;
    }
    {  // stage w row-major
      const int row = r0 + rw_ld;
      const int kg = kg0 + kw4;
      const float* src = (kg < 512) ? (P.wi2 + (size_t)row*512 + kg)
                                    : (P.wh2 + (size_t)row*128 + (kg - 512));
      *(v4f*)&wr2[rw_ld][kw4] = *(const v4f*)src;
    }
    __syncthreads();
#pragma unroll
    for (int p = 0; p < 16; ++p) {
      v2f x0 = *(const v2f*)&xs2[p*2+0][bq*2];
      v2f x1 = *(const v2f*)&xs2[p*2+1][bq*2];
#pragma unroll
      for (int ri = 0; ri < 2; ++ri) {
        v2f w = *(const v2f*)&wr2[rq*2+ri][p*2];
        acc[ri] += w[0]*x0 + w[1]*x1;
      }
    }
  }
  // store Bp[kt][b][r]
#pragma unroll
  for (int bi = 0; bi < 2; ++bi) {
    v2f st; st[0] = acc[0][bi]; st[1] = acc[1][bi];
    *(v2f*)&Bp[((size_t)kt*256 + b0 + bq*2 + bi)*512 + r0 + rq*2] = st;
  }
}

// ---------------- Phase C: LSTM2 finalize + attention + pred + x_next ----------------
__global__ void __launch_bounds__(512)
k_stepC(DecParams P, int t)
{
  __shared__ float e[NT];
  __shared__ float g2s[512];
  __shared__ float qc[256];      // [h2 | ctx]
  __shared__ float red[16];
  __shared__ float ctxp[16][132];

  const int tid = threadIdx.x;
  const int b = blockIdx.x;
  const int len = P.elen[b];
  float* Xt = P.ws + OFF_XT;
  float* C2 = P.ws + OFF_C2;
  const float* Bp = P.ws + OFF_BP;
  float* H2n = P.ws + OFF_H2 + (size_t)((t + 1) & 1) * 32768;

  // ---- LSTM2 finalize ----
  {
    const int r = tid;
    const size_t base = (size_t)b*512 + r;
    float s = Bp[base] + Bp[256*512 + base] + Bp[2*256*512 + base] + Bp[3*256*512 + base]
            + P.bi2[r] + P.bh2[r];
    g2s[r] = s;
  }
  __syncthreads();
  if (tid < 128) {
    const int j2 = tid;
    const float ig = sigm(g2s[j2]);
    const float fg = sigm(g2s[128 + j2]);
    const float gg = tanh_f(g2s[256 + j2]);
    const float og = sigm(g2s[384 + j2]);
    const float cn = fg * C2[(size_t)b*128 + j2] + ig * gg;
    C2[(size_t)b*128 + j2] = cn;
    const float h = og * tanh_f(cn);
    qc[j2] = h;
    H2n[(size_t)j2*256 + b] = h;
  }
  __syncthreads();

  // ---- energy: one row per 16-lane group, 2 rows per iter ----
  const int lg = tid & 15, grp = tid >> 4;       // 32 groups
  const v4f qa = *(const v4f*)&qc[lg*8];
  const v4f qb = *(const v4f*)&qc[lg*8 + 4];
  const v4f* kb = (const v4f*)(P.key + (size_t)b*NT*NKV);
#pragma unroll 1
  for (int s = 0; s < 13; ++s) {
    const int ta = s*64 + grp, tb = ta + 32;
    float pa = 0.0f, pb = 0.0f;
    if (ta < len) {
      v4f k0 = kb[(size_t)ta*32 + lg*2], k1 = kb[(size_t)ta*32 + lg*2 + 1];
      v4f d = k0*qa + k1*qb; pa = d[0]+d[1]+d[2]+d[3];
    }
    if (tb < len) {
      v4f k0 = kb[(size_t)tb*32 + lg*2], k1 = kb[(size_t)tb*32 + lg*2 + 1];
      v4f d = k0*qa + k1*qb; pb = d[0]+d[1]+d[2]+d[3];
    }
    pa += __shfl_xor(pa, 1); pb += __shfl_xor(pb, 1);
    pa += __shfl_xor(pa, 2); pb += __shfl_xor(pb, 2);
    pa += __shfl_xor(pa, 4); pb += __shfl_xor(pb, 4);
    pa += __shfl_xor(pa, 8); pb += __shfl_xor(pb, 8);
    if (lg == 0) {
      if (ta < len) e[ta] = pa;
      if (tb < len) e[tb] = pb;
    }
  }
  for (int tt = len + tid; tt < NT; tt += 512) e[tt] = -1e9f;
  __syncthreads();

  // ---- softmax ----
  const int wid = tid >> 6;
  const float x0 = e[tid];
  const float x1 = (tid < NT - 512) ? e[512 + tid] : -3.0e38f;
  float m = fmaxf(x0, x1);
  m = fmaxf(m, __shfl_xor(m, 1));  m = fmaxf(m, __shfl_xor(m, 2));
  m = fmaxf(m, __shfl_xor(m, 4));  m = fmaxf(m, __shfl_xor(m, 8));
  m = fmaxf(m, __shfl_xor(m, 16)); m = fmaxf(m, __shfl_xor(m, 32));
  if ((tid & 63) == 0) red[wid] = m;
  __syncthreads();
  m = red[0];
#pragma unroll
  for (int i = 1; i < 8; ++i) m = fmaxf(m, red[i]);
  const float p0 = __expf(x0 - m);
  const float p1 = (tid < NT - 512) ? __expf(x1 - m) : 0.0f;
  float ss = p0 + p1;
  ss += __shfl_xor(ss, 1);  ss += __shfl_xor(ss, 2);  ss += __shfl_xor(ss, 4);
  ss += __shfl_xor(ss, 8);  ss += __shfl_xor(ss, 16); ss += __shfl_xor(ss, 32);
  if ((tid & 63) == 0) red[8 + wid] = ss;
  __syncthreads();
  float S = red[8];
#pragma unroll
  for (int i = 1; i < 8; ++i) S += red[8 + i];
  const float inv = 1.0f / S;
  e[tid] = p0 * inv;
  if (tid < NT - 512) e[512 + tid] = p1 * inv;
  if (b == 0) {
    P.out[PRED_SIZE + (size_t)t*NT + tid] = p0 * inv;
    if (tid < NT - 512) P.out[PRED_SIZE + (size_t)t*NT + 512 + tid] = p1 * inv;
  }
  __syncthreads();

  // ---- ctx = attn @ value ----
  {
    const int kq = tid & 31, tq = tid >> 5;       // 16 t-parallel
    const v4f* vb = (const v4f*)(P.val + (size_t)b*NT*NKV);
    v4f a4 = (v4f)0.0f, a42 = (v4f)0.0f;
    int tt = tq;
    for (; tt + 16 < len; tt += 32) {
      a4  += e[tt]      * vb[(size_t)tt*32 + kq];
      a42 += e[tt + 16] * vb[(size_t)(tt + 16)*32 + kq];
    }
    if (tt < len) a4 += e[tt] * vb[(size_t)tt*32 + kq];
    a4 += a42;
    *(v4f*)&ctxp[tq][kq*4] = a4;
  }
  __syncthreads();
  if (tid < 128) {
    const int k = tid;
    float c = 0.0f;
#pragma unroll
    for (int r = 0; r < 16; ++r) c += ctxp[r][k];
    qc[128 + k] = c;
    Xt[(size_t)(256 + k)*256 + b] = c;   // x_next ctx
  }
  __syncthreads();

  // ---- pred = [h2|ctx] @ emb^T + bias ----
  {
    const int vv = tid >> 4, lg16 = tid & 15;
    if (vv < NV) {
      const v4f* er = (const v4f*)(P.emb + (size_t)vv*NE + lg16*16);
      const v4f* qr = (const v4f*)&qc[lg16*16];
      v4f s4 = er[0]*qr[0] + er[1]*qr[1] + er[2]*qr[2] + er[3]*qr[3];
      float p = s4[0] + s4[1] + s4[2] + s4[3];
      p += __shfl_xor(p, 1); p += __shfl_xor(p, 2);
      p += __shfl_xor(p, 4); p += __shfl_xor(p, 8);
      if (lg16 == 0) P.out[((size_t)b*NL + t)*NV + vv] = p + P.ob[vv];
    }
  }

  // ---- x_next: emb(y[b][t]) ----
  if (tid < 256) {
    const int tok = P.y[(size_t)b*NL + t];
    Xt[(size_t)tid*256 + b] = P.emb[(size_t)tok*NE + tid];
  }
}

extern "C" void kernel_launch(void* const* d_in, const int* in_sizes, int n_in,
                              void* d_out, int out_size, void* d_ws, size_t ws_size,
                              hipStream_t stream) {
  (void)in_sizes; (void)n_in; (void)out_size; (void)ws_size;
  DecParams P;
  P.key  = (const float*)d_in[0];
  P.val  = (const float*)d_in[1];
  P.elen = (const int*)d_in[2];
  P.y    = (const int*)d_in[3];
  P.emb  = (const float*)d_in[4];
  P.wi1  = (const float*)d_in[5];
  P.wh1  = (const float*)d_in[6];
  P.bi1  = (const float*)d_in[7];
  P.bh1  = (const float*)d_in[8];
  P.wi2  = (const float*)d_in[9];
  P.wh2  = (const float*)d_in[10];
  P.bi2  = (const float*)d_in[11];
  P.bh2  = (const float*)d_in[12];
  P.ob   = (const float*)d_in[13];
  P.out  = (float*)d_out;
  P.ws   = (float*)d_ws;

  hipLaunchKernelGGL(k_init, dim3(1792), dim3(256), 0, stream, P);
  for (int t = 0; t < NL; ++t) {
    hipLaunchKernelGGL(k_stepA, dim3(512), dim3(256), 0, stream, P);
    hipLaunchKernelGGL(k_afin,  dim3(512), dim3(256), 0, stream, P);
    hipLaunchKernelGGL(k_stepB, dim3(512), dim3(256), 0, stream, P, t);
    hipLaunchKernelGGL(k_stepC, dim3(NB),  dim3(512), 0, stream, P, t);
  }
}

// Round 4
// 14936.496 us; speedup vs baseline: 4.3747x; 1.1960x over previous
//
#include <hip/hip_runtime.h>
#include <cstddef>

// Problem constants
#define NV   30
#define NDH  512
#define NE   256
#define NKV  128
#define NB   256
#define NT   800
#define NL   300
#define NKX  896   // E + KV + DH

#define PRED_SIZE (NB*NL*NV)   // 2304000 floats; attn_plot (NL*NT) follows

typedef float v4f __attribute__((ext_vector_type(4)));
typedef float v2f __attribute__((ext_vector_type(2)));
typedef short bf16x8 __attribute__((ext_vector_type(8)));
typedef unsigned short ushort_t;

// workspace float offsets
#define OFF_XT  0                      // Xt[896][256] fp32 (only rows 384..895 = h1 used, read by B)
#define OFF_C1  229376                 // C1t[512][256]
#define OFF_H2  360448                 // H2t[2][128][256]
#define OFF_C2  425984                 // C2[256][128]
#define OFF_GP  458752                 // Gp[2][2048][256]
#define OFF_BP  1507328                // Bp[4][256][512]
#define OFF_XB  2031616                // Xb ushort[2][256][1024] (hi plane, lo plane)
#define OFF_WF  2293760                // Wf ushort[2][128][28][64][8]
// total = 5,963,776 floats = 23.9 MB

struct DecParams {
  const float* key; const float* val; const int* elen; const int* y;
  const float* emb;
  const float* wi1; const float* wh1; const float* bi1; const float* bh1;
  const float* wi2; const float* wh2; const float* bi2; const float* bh2;
  const float* ob;
  float* out; float* ws;
};

__device__ __forceinline__ float sigm(float x)  { return 1.0f/(1.0f + __expf(-x)); }
__device__ __forceinline__ float tanh_f(float x){ return 1.0f - 2.0f/(__expf(2.0f*x)+1.0f); }

__device__ __forceinline__ ushort_t bf16_rne(float x){
  union { float f; unsigned u; } v; v.f = x;
  unsigned r = v.u + 0x7FFFu + ((v.u >> 16) & 1u);
  return (ushort_t)(r >> 16);
}
__device__ __forceinline__ float bf16_to_f(ushort_t h){
  union { float f; unsigned u; } v; v.u = ((unsigned)h) << 16;
  return v.f;
}

// ---------------- init: zero Xt/C1/H2/C2 ----------------
__global__ void __launch_bounds__(256)
k_init(DecParams P)
{
  const int idx = blockIdx.x * 256 + threadIdx.x;   // grid 1792*256 = 458752
  P.ws[idx] = 0.0f;
}

// ---------------- initX: Xb bf16 planes: emb[0]=0, ctx=value[:,0,:], h1=0 ----------------
__global__ void __launch_bounds__(256)
k_initX(DecParams P)
{
  const int b = blockIdx.x, tid = threadIdx.x;
  ushort_t* xb = (ushort_t*)(P.ws + OFF_XB);
  ushort_t* xbh = xb;
  ushort_t* xbl = xb + 256*1024;
#pragma unroll
  for (int i = 0; i < 4; ++i) {
    const int k = i*256 + tid;
    float v = 0.0f;
    if (k >= 256 && k < 384) v = P.val[(size_t)b*NT*NKV + (k - 256)];
    ushort_t hi = bf16_rne(v);
    ushort_t lo = bf16_rne(v - bf16_to_f(hi));
    xbh[(size_t)b*1024 + k] = hi;
    xbl[(size_t)b*1024 + k] = lo;
  }
}

// ---------------- initW: split W1 into bf16 hi/lo, fragment-linear layout ----------------
// Wf[plane][rt16 (r>>4)][kc (k>>5)][lane][e]: lane = (r&15) | (((k>>3)&3)<<4), e = k&7
__global__ void __launch_bounds__(256)
k_initW(DecParams P)
{
  const int r = blockIdx.x;            // 0..2047
  const int tid = threadIdx.x;
  ushort_t* wf = (ushort_t*)(P.ws + OFF_WF);
  const int rt = r >> 4;
#pragma unroll
  for (int i = 0; i < 4; ++i) {
    const int k = i*256 + tid;
    if (k < NKX) {
      const float w = (k < 384) ? P.wi1[(size_t)r*384 + k]
                                : P.wh1[(size_t)r*512 + (k - 384)];
      ushort_t hi = bf16_rne(w);
      ushort_t lo = bf16_rne(w - bf16_to_f(hi));
      const int kc = k >> 5;
      const int lane = (r & 15) | (((k >> 3) & 3) << 4);
      const int e = k & 7;
      const size_t base = ((((size_t)rt)*28 + kc)*64 + lane)*8 + e;
      wf[base] = hi;
      wf[(size_t)128*28*64*8 + base] = lo;
    }
  }
}

// ---------------- Phase A: gates1 GEMM via split-bf16 MFMA ----------------
// G[r][b] = sum_k W1[r][k] X[k][b]; M=2048, N=256, K=896
// grid 256 = mt(32: 64r) x nt(4: 64b) x kt(2: K=448); 4 waves; wave w: rows rt16=mt*4+w
__global__ void __launch_bounds__(256)
k_stepA(DecParams P)
{
  __shared__ ushort_t xs[2][64][72];   // [plane][b][k(64)+pad]; row 144B, 16B-aligned
  const int tid = threadIdx.x, bid = blockIdx.x;
  const int mt = bid & 31, nt = (bid >> 5) & 3, kt = bid >> 7;
  const int w = tid >> 6, lane = tid & 63;
  const int rt16 = mt*4 + w;
  const int b0 = nt * 64;

  const ushort_t* Wf = (const ushort_t*)(P.ws + OFF_WF);
  const ushort_t* Xb = (const ushort_t*)(P.ws + OFF_XB);
  float* Gp = P.ws + OFF_GP;

  v4f acc[4];
#pragma unroll
  for (int i = 0; i < 4; ++i) acc[i] = (v4f)0.0f;

  const int srow = tid >> 2, skq = (tid & 3) * 16;
  const int lr = lane & 15, lk8 = (lane >> 4) * 8;

#pragma unroll 1
  for (int p = 0; p < 7; ++p) {
    const int kg = kt*448 + p*64;
    __syncthreads();
    {  // stage X chunk: both planes, coalesced
      const ushort_t* s0 = Xb + (size_t)(b0 + srow)*1024 + kg + skq;
      const ushort_t* s1 = s0 + (size_t)256*1024;
      *(bf16x8*)&xs[0][srow][skq]     = *(const bf16x8*)(s0);
      *(bf16x8*)&xs[0][srow][skq + 8] = *(const bf16x8*)(s0 + 8);
      *(bf16x8*)&xs[1][srow][skq]     = *(const bf16x8*)(s1);
      *(bf16x8*)&xs[1][srow][skq + 8] = *(const bf16x8*)(s1 + 8);
    }
    __syncthreads();
#pragma unroll
    for (int kc2 = 0; kc2 < 2; ++kc2) {
      const int kcg = (kg >> 5) + kc2;
      bf16x8 ah = *(const bf16x8*)(Wf + ((((size_t)0*128 + rt16)*28 + kcg)*64 + lane)*8);
      bf16x8 al = *(const bf16x8*)(Wf + ((((size_t)1*128 + rt16)*28 + kcg)*64 + lane)*8);
      const int lk = kc2*32 + lk8;
#pragma unroll
      for (int ct = 0; ct < 4; ++ct) {
        bf16x8 bh = *(const bf16x8*)&xs[0][ct*16 + lr][lk];
        bf16x8 bl = *(const bf16x8*)&xs[1][ct*16 + lr][lk];
        acc[ct] = __builtin_amdgcn_mfma_f32_16x16x32_bf16(ah, bh, acc[ct], 0, 0, 0);
        acc[ct] = __builtin_amdgcn_mfma_f32_16x16x32_bf16(ah, bl, acc[ct], 0, 0, 0);
        acc[ct] = __builtin_amdgcn_mfma_f32_16x16x32_bf16(al, bh, acc[ct], 0, 0, 0);
      }
    }
  }
  // epilogue: D col=lane&15 (b), row=(lane>>4)*4+reg (r)
  const int rg = (lane >> 4) * 4;
  const int r0 = rt16 * 16;
#pragma unroll
  for (int ct = 0; ct < 4; ++ct)
#pragma unroll
    for (int j = 0; j < 4; ++j)
      Gp[((size_t)kt*2048 + r0 + rg + j)*256 + b0 + ct*16 + lr] = acc[ct][j];
}

// ---------------- Afin: sum partials + LSTM1 activations ----------------
// grid 512 (j), 256 threads (b). h1 -> Xt[384+j][b] (fp32, for B) + Xb[b][384+j] (bf16, for A)
__global__ void __launch_bounds__(256)
k_afin(DecParams P)
{
  const int j = blockIdx.x;
  const int b = threadIdx.x;
  const float* Gp = P.ws + OFF_GP;
  float* Xt = P.ws + OFF_XT;
  float* C1 = P.ws + OFF_C1;
  ushort_t* xb = (ushort_t*)(P.ws + OFF_XB);

  float s[4];
#pragma unroll
  for (int g = 0; g < 4; ++g) {
    const size_t base = ((size_t)g*512 + j)*256 + b;
    s[g] = Gp[base] + Gp[(size_t)2048*256 + base]
         + P.bi1[g*512 + j] + P.bh1[g*512 + j];
  }
  const float ig = sigm(s[0]);
  const float fg = sigm(s[1]);
  const float gg = tanh_f(s[2]);
  const float og = sigm(s[3]);
  const float cn = fg * C1[(size_t)j*256 + b] + ig * gg;
  C1[(size_t)j*256 + b] = cn;
  const float h = og * tanh_f(cn);
  Xt[(size_t)(384 + j)*256 + b] = h;
  ushort_t hi = bf16_rne(h);
  ushort_t lo = bf16_rne(h - bf16_to_f(hi));
  xb[(size_t)b*1024 + 384 + j] = hi;
  xb[(size_t)256*1024 + (size_t)b*1024 + 384 + j] = lo;
}

// ---------------- Phase B: gates2 partial GEMM (fp32) ----------------
__global__ void __launch_bounds__(256)
k_stepB(DecParams P, int t)
{
  __shared__ float xs2[32][36];
  __shared__ float wr2[32][36];
  const int tid = threadIdx.x;
  const int bid = blockIdx.x;
  const int bt = bid & 7, jt = (bid >> 3) & 15, kt = bid >> 7;
  const int b0 = bt * 32, r0 = jt * 32;
  const int bq = tid & 15, rq = tid >> 4;

  const float* Xt = P.ws + OFF_XT;
  const float* H2p = P.ws + OFF_H2 + (size_t)(t & 1) * 32768;
  float* Bp = P.ws + OFF_BP;

  v2f acc[2] = {(v2f)0.0f, (v2f)0.0f};

  const int kx_ld = tid >> 3, bx4 = (tid & 7) * 4;
  const int rw_ld = tid >> 3, kw4 = (tid & 7) * 4;

#pragma unroll 1
  for (int cc = 0; cc < 5; ++cc) {
    const int kg0 = kt * 160 + cc * 32;
    __syncthreads();
    {
      const int kg = kg0 + kx_ld;
      const float* src = (kg < 512) ? (Xt + (size_t)(384 + kg)*256 + b0 + bx4)
                                    : (H2p + (size_t)(kg - 512)*256 + b0 + bx4);
      *(v4f*)&xs2[kx_ld][bx4] = *(const v4f*)src;
    }
    {
      const int row = r0 + rw_ld;
      const int kg = kg0 + kw4;
      const float* src = (kg < 512) ? (P.wi2 + (size_t)row*512 + kg)
                                    : (P.wh2 + (size_t)row*128 + (kg - 512));
      *(v4f*)&wr2[rw_ld][kw4] = *(const v4f*)src;
    }
    __syncthreads();
#pragma unroll
    for (int p = 0; p < 16; ++p) {
      v2f x0 = *(const v2f*)&xs2[p*2+0][bq*2];
      v2f x1 = *(const v2f*)&xs2[p*2+1][bq*2];
#pragma unroll
      for (int ri = 0; ri < 2; ++ri) {
        v2f w = *(const v2f*)&wr2[rq*2+ri][p*2];
        acc[ri] += w[0]*x0 + w[1]*x1;
      }
    }
  }
#pragma unroll
  for (int bi = 0; bi < 2; ++bi) {
    v2f st; st[0] = acc[0][bi]; st[1] = acc[1][bi];
    *(v2f*)&Bp[((size_t)kt*256 + b0 + bq*2 + bi)*512 + r0 + rq*2] = st;
  }
}

// ---------------- Phase C: LSTM2 finalize + attention + pred + x_next ----------------
__global__ void __launch_bounds__(512)
k_stepC(DecParams P, int t)
{
  __shared__ float e[NT];
  __shared__ float g2s[512];
  __shared__ float qc[256];      // [h2 | ctx]
  __shared__ float red[16];
  __shared__ float ctxp[16][132];

  const int tid = threadIdx.x;
  const int b = blockIdx.x;
  const int len = P.elen[b];
  float* C2 = P.ws + OFF_C2;
  const float* Bp = P.ws + OFF_BP;
  float* H2n = P.ws + OFF_H2 + (size_t)((t + 1) & 1) * 32768;
  ushort_t* xbh = (ushort_t*)(P.ws + OFF_XB);
  ushort_t* xbl = xbh + (size_t)256*1024;

  // ---- LSTM2 finalize ----
  {
    const int r = tid;
    const size_t base = (size_t)b*512 + r;
    float s = Bp[base] + Bp[256*512 + base] + Bp[2*256*512 + base] + Bp[3*256*512 + base]
            + P.bi2[r] + P.bh2[r];
    g2s[r] = s;
  }
  __syncthreads();
  if (tid < 128) {
    const int j2 = tid;
    const float ig = sigm(g2s[j2]);
    const float fg = sigm(g2s[128 + j2]);
    const float gg = tanh_f(g2s[256 + j2]);
    const float og = sigm(g2s[384 + j2]);
    const float cn = fg * C2[(size_t)b*128 + j2] + ig * gg;
    C2[(size_t)b*128 + j2] = cn;
    const float h = og * tanh_f(cn);
    qc[j2] = h;
    H2n[(size_t)j2*256 + b] = h;
  }
  __syncthreads();

  // ---- energy ----
  const int lg = tid & 15, grp = tid >> 4;
  const v4f qa = *(const v4f*)&qc[lg*8];
  const v4f qb = *(const v4f*)&qc[lg*8 + 4];
  const v4f* kb = (const v4f*)(P.key + (size_t)b*NT*NKV);
#pragma unroll 1
  for (int s = 0; s < 13; ++s) {
    const int ta = s*64 + grp, tb = ta + 32;
    float pa = 0.0f, pb = 0.0f;
    if (ta < len) {
      v4f k0 = kb[(size_t)ta*32 + lg*2], k1 = kb[(size_t)ta*32 + lg*2 + 1];
      v4f d = k0*qa + k1*qb; pa = d[0]+d[1]+d[2]+d[3];
    }
    if (tb < len) {
      v4f k0 = kb[(size_t)tb*32 + lg*2], k1 = kb[(size_t)tb*32 + lg*2 + 1];
      v4f d = k0*qa + k1*qb; pb = d[0]+d[1]+d[2]+d[3];
    }
    pa += __shfl_xor(pa, 1); pb += __shfl_xor(pb, 1);
    pa += __shfl_xor(pa, 2); pb += __shfl_xor(pb, 2);
    pa += __shfl_xor(pa, 4); pb += __shfl_xor(pb, 4);
    pa += __shfl_xor(pa, 8); pb += __shfl_xor(pb, 8);
    if (lg == 0) {
      if (ta < len) e[ta] = pa;
      if (tb < len) e[tb] = pb;
    }
  }
  for (int tt = len + tid; tt < NT; tt += 512) e[tt] = -1e9f;
  __syncthreads();

  // ---- softmax ----
  const int wid = tid >> 6;
  const float x0 = e[tid];
  const float x1 = (tid < NT - 512) ? e[512 + tid] : -3.0e38f;
  float m = fmaxf(x0, x1);
  m = fmaxf(m, __shfl_xor(m, 1));  m = fmaxf(m, __shfl_xor(m, 2));
  m = fmaxf(m, __shfl_xor(m, 4));  m = fmaxf(m, __shfl_xor(m, 8));
  m = fmaxf(m, __shfl_xor(m, 16)); m = fmaxf(m, __shfl_xor(m, 32));
  if ((tid & 63) == 0) red[wid] = m;
  __syncthreads();
  m = red[0];
#pragma unroll
  for (int i = 1; i < 8; ++i) m = fmaxf(m, red[i]);
  const float p0 = __expf(x0 - m);
  const float p1 = (tid < NT - 512) ? __expf(x1 - m) : 0.0f;
  float ss = p0 + p1;
  ss += __shfl_xor(ss, 1);  ss += __shfl_xor(ss, 2);  ss += __shfl_xor(ss, 4);
  ss += __shfl_xor(ss, 8);  ss += __shfl_xor(ss, 16); ss += __shfl_xor(ss, 32);
  if ((tid & 63) == 0) red[8 + wid] = ss;
  __syncthreads();
  float S = red[8];
#pragma unroll
  for (int i = 1; i < 8; ++i) S += red[8 + i];
  const float inv = 1.0f / S;
  e[tid] = p0 * inv;
  if (tid < NT - 512) e[512 + tid] = p1 * inv;
  if (b == 0) {
    P.out[PRED_SIZE + (size_t)t*NT + tid] = p0 * inv;
    if (tid < NT - 512) P.out[PRED_SIZE + (size_t)t*NT + 512 + tid] = p1 * inv;
  }
  __syncthreads();

  // ---- ctx = attn @ value ----
  {
    const int kq = tid & 31, tq = tid >> 5;
    const v4f* vb = (const v4f*)(P.val + (size_t)b*NT*NKV);
    v4f a4 = (v4f)0.0f, a42 = (v4f)0.0f;
    int tt = tq;
    for (; tt + 16 < len; tt += 32) {
      a4  += e[tt]      * vb[(size_t)tt*32 + kq];
      a42 += e[tt + 16] * vb[(size_t)(tt + 16)*32 + kq];
    }
    if (tt < len) a4 += e[tt] * vb[(size_t)tt*32 + kq];
    a4 += a42;
    *(v4f*)&ctxp[tq][kq*4] = a4;
  }
  __syncthreads();
  if (tid < 128) {
    const int k = tid;
    float c = 0.0f;
#pragma unroll
    for (int r = 0; r < 16; ++r) c += ctxp[r][k];
    qc[128 + k] = c;
    ushort_t hi = bf16_rne(c);
    ushort_t lo = bf16_rne(c - bf16_to_f(hi));
    xbh[(size_t)b*1024 + 256 + k] = hi;    // x_next ctx (bf16 planes)
    xbl[(size_t)b*1024 + 256 + k] = lo;
  }
  __syncthreads();

  // ---- pred = [h2|ctx] @ emb^T + bias ----
  {
    const int vv = tid >> 4, lg16 = tid & 15;
    if (vv < NV) {
      const v4f* er = (const v4f*)(P.emb + (size_t)vv*NE + lg16*16);
      const v4f* qr = (const v4f*)&qc[lg16*16];
      v4f s4 = er[0]*qr[0] + er[1]*qr[1] + er[2]*qr[2] + er[3]*qr[3];
      float p = s4[0] + s4[1] + s4[2] + s4[3];
      p += __shfl_xor(p, 1); p += __shfl_xor(p, 2);
      p += __shfl_xor(p, 4); p += __shfl_xor(p, 8);
      if (lg16 == 0) P.out[((size_t)b*NL + t)*NV + vv] = p + P.ob[vv];
    }
  }

  // ---- x_next: emb(y[b][t]) -> Xb bf16 planes ----
  if (tid < 256) {
    const int tok = P.y[(size_t)b*NL + t];
    const float x = P.emb[(size_t)tok*NE + tid];
    ushort_t hi = bf16_rne(x);
    ushort_t lo = bf16_rne(x - bf16_to_f(hi));
    xbh[(size_t)b*1024 + tid] = hi;
    xbl[(size_t)b*1024 + tid] = lo;
  }
}

extern "C" void kernel_launch(void* const* d_in, const int* in_sizes, int n_in,
                              void* d_out, int out_size, void* d_ws, size_t ws_size,
                              hipStream_t stream) {
  (void)in_sizes; (void)n_in; (void)out_size; (void)ws_size;
  DecParams P;
  P.key  = (const float*)d_in[0];
  P.val  = (const float*)d_in[1];
  P.elen = (const int*)d_in[2];
  P.y    = (const int*)d_in[3];
  P.emb  = (const float*)d_in[4];
  P.wi1  = (const float*)d_in[5];
  P.wh1  = (const float*)d_in[6];
  P.bi1  = (const float*)d_in[7];
  P.bh1  = (const float*)d_in[8];
  P.wi2  = (const float*)d_in[9];
  P.wh2  = (const float*)d_in[10];
  P.bi2  = (const float*)d_in[11];
  P.bh2  = (const float*)d_in[12];
  P.ob   = (const float*)d_in[13];
  P.out  = (float*)d_out;
  P.ws   = (float*)d_ws;

  hipLaunchKernelGGL(k_init,  dim3(1792), dim3(256), 0, stream, P);
  hipLaunchKernelGGL(k_initX, dim3(256),  dim3(256), 0, stream, P);
  hipLaunchKernelGGL(k_initW, dim3(2048), dim3(256), 0, stream, P);
  for (int t = 0; t < NL; ++t) {
    hipLaunchKernelGGL(k_stepA, dim3(256), dim3(256), 0, stream, P);
    hipLaunchKernelGGL(k_afin,  dim3(512), dim3(256), 0, stream, P);
    hipLaunchKernelGGL(k_stepB, dim3(512), dim3(256), 0, stream, P, t);
    hipLaunchKernelGGL(k_stepC, dim3(NB),  dim3(512), 0, stream, P, t);
  }
}